// Round 8
// baseline (293.727 us; speedup 1.0000x reference)
//
#include <hip/hip_runtime.h>
#include <hip/hip_bf16.h>

#define T_SEQ 1024
#define U_DIM 512
#define LN_EPS 1e-3f

typedef float  f32x4  __attribute__((ext_vector_type(4)));
typedef short  bf16x8 __attribute__((ext_vector_type(8)));

__device__ __forceinline__ unsigned short f2bf(float f) {
    union { float f; unsigned u; } x; x.f = f;
    unsigned r = x.u + 0x7fffu + ((x.u >> 16) & 1u);   // RNE
    return (unsigned short)(r >> 16);
}
__device__ __forceinline__ float b2f(short s) {
    union { unsigned u; float f; } x; x.u = ((unsigned)(unsigned short)s) << 16;
    return x.f;
}
__device__ __forceinline__ int packbf(float a, float b) {
    return (int)((unsigned)f2bf(a) | ((unsigned)f2bf(b) << 16));
}

// ---------------------------------------------------------------------------
// prep_all: bid<256 -> W fp32 -> Wt[n][k] bf16; else q/k/v fp32 -> bf16 copies.
// ---------------------------------------------------------------------------
__global__ __launch_bounds__(256) void prep_all(
        const float* __restrict__ Wq, const float* __restrict__ Wk,
        const float* __restrict__ Wv, const float* __restrict__ Wo,
        short* __restrict__ wt,
        const float* __restrict__ q, const float* __restrict__ k,
        const float* __restrict__ v,
        short* __restrict__ qb, short* __restrict__ kb, short* __restrict__ vb) {
    __shared__ float Ws[64][65];
    const int bid = blockIdx.x, t = threadIdx.x;
    if (bid < 256) {
        const int z = bid >> 6, tile = bid & 63;
        const float* W = (z == 0) ? Wq : (z == 1) ? Wk : (z == 2) ? Wv : Wo;
        short* Wt = wt + (size_t)z * 262144;
        const int k0 = (tile >> 3) * 64, n0 = (tile & 7) * 64;
        {
            const int kr = t >> 2, cs = (t & 3) * 16;
            const float4* src = (const float4*)(W + (size_t)(k0 + kr) * 512 + n0 + cs);
#pragma unroll
            for (int i = 0; i < 4; ++i) {
                float4 vv = src[i];
                Ws[kr][cs + 4 * i + 0] = vv.x;
                Ws[kr][cs + 4 * i + 1] = vv.y;
                Ws[kr][cs + 4 * i + 2] = vv.z;
                Ws[kr][cs + 4 * i + 3] = vv.w;
            }
        }
        __syncthreads();
        {
            const int nr = t >> 2, ks = (t & 3) * 16;
            int4 w0, w1;
            w0.x = packbf(Ws[ks + 0][nr], Ws[ks + 1][nr]);
            w0.y = packbf(Ws[ks + 2][nr], Ws[ks + 3][nr]);
            w0.z = packbf(Ws[ks + 4][nr], Ws[ks + 5][nr]);
            w0.w = packbf(Ws[ks + 6][nr], Ws[ks + 7][nr]);
            w1.x = packbf(Ws[ks + 8][nr], Ws[ks + 9][nr]);
            w1.y = packbf(Ws[ks + 10][nr], Ws[ks + 11][nr]);
            w1.z = packbf(Ws[ks + 12][nr], Ws[ks + 13][nr]);
            w1.w = packbf(Ws[ks + 14][nr], Ws[ks + 15][nr]);
            short* dst = Wt + (size_t)(n0 + nr) * 512 + k0 + ks;
            *(int4*)dst = w0;
            *(int4*)(dst + 8) = w1;
        }
    } else {
        const int aid = bid - 256;
        const int tsr = aid >> 10, chunk = aid & 1023;
        const float* src = ((tsr == 0) ? q : (tsr == 1) ? k : v) + (size_t)chunk * 4096 + t * 16;
        short* dst = ((tsr == 0) ? qb : (tsr == 1) ? kb : vb) + (size_t)chunk * 4096 + t * 16;
        float4 f0 = ((const float4*)src)[0];
        float4 f1 = ((const float4*)src)[1];
        float4 f2 = ((const float4*)src)[2];
        float4 f3 = ((const float4*)src)[3];
        int4 o0, o1;
        o0.x = packbf(f0.x, f0.y); o0.y = packbf(f0.z, f0.w);
        o0.z = packbf(f1.x, f1.y); o0.w = packbf(f1.z, f1.w);
        o1.x = packbf(f2.x, f2.y); o1.y = packbf(f2.z, f2.w);
        o1.z = packbf(f3.x, f3.y); o1.w = packbf(f3.z, f3.w);
        *(int4*)dst = o0;
        *(int4*)(dst + 8) = o1;
    }
}

// ---------------------------------------------------------------------------
// Barrier-free, LDS-free MFMA GEMM: out = relu(A[8192,512]bf16 @ W + bias).
// Fragments loaded directly from global (L2-resident Wt; A re-read 4x).
// OUT=0: bf16 out row-major, EXCEPT z==2 writes transposed vT[hb][d][s].
// OUT=1: fp32 out + residual after relu.
// ---------------------------------------------------------------------------
template <int OUT>
__global__ __launch_bounds__(256) void gemm_nolds(
        const short* __restrict__ A0, const short* __restrict__ A1, const short* __restrict__ A2,
        const short* __restrict__ Wt0, const short* __restrict__ Wt1, const short* __restrict__ Wt2,
        const float* __restrict__ b0p, const float* __restrict__ b1p, const float* __restrict__ b2p,
        const float* __restrict__ resid,
        void* __restrict__ O0, void* __restrict__ O1, void* __restrict__ O2) {
    const int z = blockIdx.z;
    const short* Az = (z == 0) ? A0 : (z == 1) ? A1 : A2;
    const short* Wz = (z == 0) ? Wt0 : (z == 1) ? Wt1 : Wt2;
    const float* bz = (z == 0) ? b0p : (z == 1) ? b1p : b2p;
    void* Ov = (z == 0) ? O0 : (z == 1) ? O1 : O2;

    const int tid = threadIdx.x;
    const int m0 = blockIdx.x * 128, n0 = blockIdx.y * 128;
    const int w = tid >> 6, lane = tid & 63;
    const int n15 = lane & 15, g = lane >> 4;
    const int mh = w >> 1, nh = w & 1;

    const short* Ab = Az + (size_t)(m0 + mh * 64 + n15) * 512 + g * 8;
    const short* Bb = Wz + (size_t)(n0 + nh * 64 + n15) * 512 + g * 8;

    f32x4 acc[4][4];
#pragma unroll
    for (int i = 0; i < 4; ++i)
#pragma unroll
        for (int j = 0; j < 4; ++j) acc[i][j] = (f32x4){0.f, 0.f, 0.f, 0.f};

    bf16x8 af[4], bfv[4];
#pragma unroll
    for (int t = 0; t < 4; ++t) {
        af[t]  = *(const bf16x8*)(Ab + t * 16 * 512);
        bfv[t] = *(const bf16x8*)(Bb + t * 16 * 512);
    }
#pragma unroll
    for (int kk = 0; kk < 16; ++kk) {     // K32 steps, prefetch one ahead
        bf16x8 afn[4], bfn[4];
        if (kk < 15) {
            const int ko = (kk + 1) * 32;
#pragma unroll
            for (int t = 0; t < 4; ++t) {
                afn[t] = *(const bf16x8*)(Ab + t * 16 * 512 + ko);
                bfn[t] = *(const bf16x8*)(Bb + t * 16 * 512 + ko);
            }
        }
#pragma unroll
        for (int i = 0; i < 4; ++i)
#pragma unroll
            for (int j = 0; j < 4; ++j)
                acc[i][j] = __builtin_amdgcn_mfma_f32_16x16x32_bf16(af[i], bfv[j], acc[i][j], 0, 0, 0);
        if (kk < 15) {
#pragma unroll
            for (int t = 0; t < 4; ++t) { af[t] = afn[t]; bfv[t] = bfn[t]; }
        }
    }

    // Epilogue
    const int mbase = m0 + mh * 64 + g * 4;
    const int nbase = n0 + nh * 64 + n15;
    const bool even = (n15 & 1) == 0;
    float bj[4];
#pragma unroll
    for (int j = 0; j < 4; ++j) bj[j] = bz[nbase + j * 16];

    if (OUT == 0 && z == 2) {
        // transposed store into vT[hb][d][s] (Ov = vT)
        const int b = m0 >> 10;
        const int sbase = (m0 & 1023) + mh * 64 + g * 4;
        short* vTo = (short*)Ov;
#pragma unroll
        for (int i = 0; i < 4; ++i) {
            const int srow = sbase + i * 16;
#pragma unroll
            for (int j = 0; j < 4; ++j) {
                const int col = nbase + j * 16;
                const int h = col >> 6, d = col & 63;
                f32x4 a = acc[i][j];
                int2 pv;
                pv.x = packbf(fmaxf(a[0] + bj[j], 0.f), fmaxf(a[1] + bj[j], 0.f));
                pv.y = packbf(fmaxf(a[2] + bj[j], 0.f), fmaxf(a[3] + bj[j], 0.f));
                *(int2*)(vTo + (size_t)(h * 8 + b) * 65536 + d * 1024 + srow) = pv;
            }
        }
        return;
    }

#pragma unroll
    for (int i = 0; i < 4; ++i) {
        const int mrow = mbase + i * 16;
#pragma unroll
        for (int j = 0; j < 4; ++j) {
            const int ncol = nbase + j * 16;
            f32x4 a = acc[i][j];
            float v0 = fmaxf(a[0] + bj[j], 0.f);
            float v1 = fmaxf(a[1] + bj[j], 0.f);
            float v2 = fmaxf(a[2] + bj[j], 0.f);
            float v3 = fmaxf(a[3] + bj[j], 0.f);
            if (OUT == 0) {
                unsigned t01 = (unsigned)packbf(v0, v1);
                unsigned t23 = (unsigned)packbf(v2, v3);
                unsigned x01 = (unsigned)__shfl_xor((int)t01, 1, 64);
                unsigned x23 = (unsigned)__shfl_xor((int)t23, 1, 64);
                short* Oz = (short*)Ov;
                if (even) {
                    unsigned d0 = (t01 & 0xffffu) | (x01 << 16);
                    unsigned d1 = (t01 >> 16) | (x01 & 0xffff0000u);
                    *(unsigned*)(Oz + (size_t)(mrow + 0) * 512 + ncol) = d0;
                    *(unsigned*)(Oz + (size_t)(mrow + 1) * 512 + ncol) = d1;
                } else {
                    unsigned d2 = (x23 & 0xffffu) | (t23 << 16);
                    unsigned d3 = (x23 >> 16) | (t23 & 0xffff0000u);
                    *(unsigned*)(Oz + (size_t)(mrow + 2) * 512 + ncol - 1) = d2;
                    *(unsigned*)(Oz + (size_t)(mrow + 3) * 512 + ncol - 1) = d3;
                }
            } else {
                float x0 = __shfl_xor(v0, 1, 64);
                float x1 = __shfl_xor(v1, 1, 64);
                float x2 = __shfl_xor(v2, 1, 64);
                float x3 = __shfl_xor(v3, 1, 64);
                float* Oz = (float*)Ov;
                if (even) {
                    float2 r0 = *(const float2*)(resid + (size_t)(mrow + 0) * 512 + ncol);
                    float2 r1 = *(const float2*)(resid + (size_t)(mrow + 1) * 512 + ncol);
                    *(float2*)(Oz + (size_t)(mrow + 0) * 512 + ncol) = make_float2(v0 + r0.x, x0 + r0.y);
                    *(float2*)(Oz + (size_t)(mrow + 1) * 512 + ncol) = make_float2(v1 + r1.x, x1 + r1.y);
                } else {
                    float2 r2 = *(const float2*)(resid + (size_t)(mrow + 2) * 512 + ncol - 1);
                    float2 r3 = *(const float2*)(resid + (size_t)(mrow + 3) * 512 + ncol - 1);
                    *(float2*)(Oz + (size_t)(mrow + 2) * 512 + ncol - 1) = make_float2(x2 + r2.x, v2 + r2.y);
                    *(float2*)(Oz + (size_t)(mrow + 3) * 512 + ncol - 1) = make_float2(x3 + r3.x, v3 + r3.y);
                }
            }
        }
    }
}

// ---------------------------------------------------------------------------
// Barrier-free MFMA flash attention. Block = 4 independent waves x 16 q rows;
// block bx runs q-tile pair {bx, 15-bx} (uniform 17 steps). K fragments direct
// from ke; V fragments direct from pre-transposed vT[hb][d][s]. Only LDS is
// the per-wave qpe table (no __syncthreads anywhere).
// ---------------------------------------------------------------------------
__global__ __launch_bounds__(256) void attn_mfma(
        const short* __restrict__ qe, const short* __restrict__ ke,
        const short* __restrict__ vT, const float* __restrict__ pe_k,
        float* __restrict__ ml, short* __restrict__ ao) {
    __shared__ float qpeS[4 * 16 * 17];

    const int tid = threadIdx.x;
    const int bx = blockIdx.x;
    const int hb = blockIdx.y;
    const int h = hb >> 3, b = hb & 7;
    const int w = tid >> 6, lane = tid & 63;
    const int g = lane >> 4, n15 = lane & 15;
    float* qpeW = qpeS + w * (16 * 17);
    const size_t rowbase = (size_t)b * T_SEQ;
    const short* kbase = ke + (rowbase + n15) * 512 + h * 64 + g * 8;
    const short* vbase = vT + (size_t)hb * 65536 + n15 * 1024 + g * 8;

#pragma unroll 1
    for (int ph = 0; ph < 2; ++ph) {
        const int tile = (ph == 0) ? bx : 15 - bx;
        const int qn = tile * 64 + w * 16;

        // Q B-fragments
        bf16x8 Bq[2];
#pragma unroll
        for (int kh = 0; kh < 2; ++kh)
            Bq[kh] = *(const bf16x8*)(qe + (rowbase + qn + n15) * U_DIM + h * 64 + kh * 32 + g * 8);

        // qpe[q][ri] = Q[q]·pe_k[ri] via MFMA
        {
            f32x4 qa[2];
            qa[0] = (f32x4){0.f, 0.f, 0.f, 0.f};
            qa[1] = (f32x4){0.f, 0.f, 0.f, 0.f};
#pragma unroll
            for (int mt = 0; mt < 2; ++mt)
#pragma unroll
            for (int kh = 0; kh < 2; ++kh) {
                const float* src = pe_k + (mt * 16 + n15) * 64 + kh * 32 + g * 8;
                float4 f0 = *(const float4*)src;
                float4 f1 = *(const float4*)(src + 4);
                bf16x8 fr;
                fr[0] = (short)f2bf(f0.x); fr[1] = (short)f2bf(f0.y);
                fr[2] = (short)f2bf(f0.z); fr[3] = (short)f2bf(f0.w);
                fr[4] = (short)f2bf(f1.x); fr[5] = (short)f2bf(f1.y);
                fr[6] = (short)f2bf(f1.z); fr[7] = (short)f2bf(f1.w);
                qa[mt] = __builtin_amdgcn_mfma_f32_16x16x32_bf16(fr, Bq[kh], qa[mt], 0, 0, 0);
            }
#pragma unroll
            for (int mt = 0; mt < 2; ++mt)
#pragma unroll
            for (int r = 0; r < 4; ++r) {
                const int ri = mt * 16 + 4 * g + r;
                if (ri <= 16) qpeW[n15 * 17 + ri] = qa[mt][r];
            }
        }
        const float qpe0 = qpeW[n15 * 17];

        float m_r = -3.0e38f, l_r = 0.f;
        f32x4 oacc[4];
#pragma unroll
        for (int dt = 0; dt < 4; ++dt) oacc[dt] = (f32x4){0.f, 0.f, 0.f, 0.f};

        const int qg = qn + n15;
        for (int s0 = 0; s0 <= qn + 15; s0 += 64) {
            int cls[4];
#pragma unroll
            for (int mt = 0; mt < 4; ++mt) {
                const int slo = s0 + mt * 16;
                cls[mt] = (slo > qn + 15) ? 0 : ((slo + 31 < qn) ? 1 : 2);
            }

            // S^T = K·Q^T (fragments direct from global)
            f32x4 c[4];
#pragma unroll
            for (int mt = 0; mt < 4; ++mt) c[mt] = (f32x4){0.f, 0.f, 0.f, 0.f};
#pragma unroll
            for (int mt = 0; mt < 4; ++mt) {
                if (!cls[mt]) continue;
                const short* kp = kbase + (size_t)(s0 + mt * 16) * 512;
#pragma unroll
                for (int kh = 0; kh < 2; ++kh) {
                    bf16x8 ak = *(const bf16x8*)(kp + kh * 32);
                    c[mt] = __builtin_amdgcn_mfma_f32_16x16x32_bf16(ak, Bq[kh], c[mt], 0, 0, 0);
                }
            }

            float sc[4][4];
            float pmax = -3.0e38f;
#pragma unroll
            for (int mt = 0; mt < 4; ++mt) {
                if (cls[mt] == 0) {
#pragma unroll
                    for (int r = 0; r < 4; ++r) sc[mt][r] = -3.0e38f;
                } else if (cls[mt] == 1) {
#pragma unroll
                    for (int r = 0; r < 4; ++r) {
                        sc[mt][r] = (c[mt][r] + qpe0) * 0.125f;
                        pmax = fmaxf(pmax, sc[mt][r]);
                    }
                } else {
#pragma unroll
                    for (int r = 0; r < 4; ++r) {
                        const int sg = s0 + mt * 16 + 4 * g + r;
                        const int dlt = sg - qg;
                        if (dlt <= 0) {
                            const int ri = (dlt < -16) ? 0 : (dlt + 16);
                            sc[mt][r] = (c[mt][r] + qpeW[n15 * 17 + ri]) * 0.125f;
                            pmax = fmaxf(pmax, sc[mt][r]);
                        } else {
                            sc[mt][r] = -3.0e38f;
                        }
                    }
                }
            }
            pmax = fmaxf(pmax, __shfl_xor(pmax, 16, 64));
            pmax = fmaxf(pmax, __shfl_xor(pmax, 32, 64));
            const float mnew = fmaxf(m_r, pmax);
            const float alpha = __expf(m_r - mnew);
            float p[4][4];
            float psum = 0.f;
#pragma unroll
            for (int mt = 0; mt < 4; ++mt)
#pragma unroll
            for (int r = 0; r < 4; ++r) {
                const float pv = (cls[mt] == 0) ? 0.f : __expf(sc[mt][r] - mnew);
                p[mt][r] = pv;
                psum += pv;
            }
            psum += __shfl_xor(psum, 16, 64);
            psum += __shfl_xor(psum, 32, 64);
            l_r = l_r * alpha + psum;
            m_r = mnew;

            // P: C-layout -> A-layout in-register
            int pk01[4], pk23[4];
#pragma unroll
            for (int mt = 0; mt < 4; ++mt) {
                pk01[mt] = packbf(p[mt][0], p[mt][1]);
                pk23[mt] = packbf(p[mt][2], p[mt][3]);
            }
            const int srcA = ((g & 1) * 2) * 16 + n15;
            const int srcB = srcA + 16;
            const bool selHi = (g >> 1) != 0;
            float aO[4];
#pragma unroll
            for (int r = 0; r < 4; ++r) aO[r] = __shfl(alpha, 4 * g + r, 64);
#pragma unroll
            for (int dt = 0; dt < 4; ++dt)
#pragma unroll
            for (int r = 0; r < 4; ++r) oacc[dt][r] *= aO[r];
#pragma unroll
            for (int kh = 0; kh < 2; ++kh) {
                if (cls[2 * kh] == 0 && cls[2 * kh + 1] == 0) continue;
                const int a0l = __shfl(pk01[2 * kh], srcA, 64);
                const int a0h = __shfl(pk01[2 * kh + 1], srcA, 64);
                const int a1l = __shfl(pk23[2 * kh], srcA, 64);
                const int a1h = __shfl(pk23[2 * kh + 1], srcA, 64);
                const int a2l = __shfl(pk01[2 * kh], srcB, 64);
                const int a2h = __shfl(pk01[2 * kh + 1], srcB, 64);
                const int a3l = __shfl(pk23[2 * kh], srcB, 64);
                const int a3h = __shfl(pk23[2 * kh + 1], srcB, 64);
                union { int i[4]; bf16x8 v; } au;
                au.i[0] = selHi ? a0h : a0l;
                au.i[1] = selHi ? a1h : a1l;
                au.i[2] = selHi ? a2h : a2l;
                au.i[3] = selHi ? a3h : a3l;
                const short* vp = vbase + s0 + kh * 32;
#pragma unroll
                for (int dt = 0; dt < 4; ++dt) {
                    bf16x8 bv = *(const bf16x8*)(vp + dt * 16 * 1024);
                    oacc[dt] = __builtin_amdgcn_mfma_f32_16x16x32_bf16(au.v, bv, oacc[dt], 0, 0, 0);
                }
            }
        }

        // flush tile
        if (g == 0)
            *(float2*)(ml + ((size_t)hb * T_SEQ + qn + n15) * 2) = make_float2(m_r, l_r);
#pragma unroll
        for (int r = 0; r < 4; ++r) {
            const float lq = __shfl(l_r, 4 * g + r, 64);
            const float linv = 1.0f / lq;
            short* dst = ao + (rowbase + qn + 4 * g + r) * U_DIM + h * 64 + n15;
#pragma unroll
            for (int dt = 0; dt < 4; ++dt)
                dst[dt * 16] = (short)f2bf(oacc[dt][r] * linv);
        }
    }
}

// ---------------------------------------------------------------------------
// band_relv: recompute 17-wide diagonal band softmax weights from (m,l),
// add rel-v term (far mass = 1 - band mass goes to pe_v[0]) into ao (RMW).
// ---------------------------------------------------------------------------
__global__ __launch_bounds__(256) void band_relv(
        const short* __restrict__ qe, const short* __restrict__ ke,
        const float* __restrict__ pe_k, const float* __restrict__ pe_v,
        const float* __restrict__ ml, short* __restrict__ ao) {
    __shared__ float pek[17 * 64];
    __shared__ float pev[17 * 64];
    const int tb = blockIdx.x, hb = blockIdx.y;
    const int h = hb >> 3, b = hb & 7;
    const int tid = threadIdx.x;
    for (int i = tid; i < 17 * 64; i += 256) {
        pek[i] = b2f((short)f2bf(pe_k[i]));   // match main kernel's bf16 rounding
        pev[i] = pe_v[i];
    }
    __syncthreads();

    const int t = tb * 64 + (tid >> 2);
    const int p = (tid & 3) * 16;
    const short* qp = qe + (size_t)(b * T_SEQ + t) * U_DIM + h * 64 + p;
    bf16x8 qa = *(const bf16x8*)qp, qb2 = *(const bf16x8*)(qp + 8);
    float qv[16];
#pragma unroll
    for (int i = 0; i < 8; ++i) { qv[i] = b2f(qa[i]); qv[8 + i] = b2f(qb2[i]); }

    float dots[17];
#pragma unroll
    for (int ri = 0; ri < 17; ++ri) {
        const int s = t - 16 + ri;
        float acc = 0.f;
        if (s >= 0) {
            const short* kp = ke + (size_t)(b * T_SEQ + s) * U_DIM + h * 64 + p;
            bf16x8 ka = *(const bf16x8*)kp, kb2 = *(const bf16x8*)(kp + 8);
#pragma unroll
            for (int d = 0; d < 8; ++d) {
                acc += qv[d] * b2f(ka[d]);
                acc += qv[8 + d] * b2f(kb2[d]);
            }
#pragma unroll
            for (int d = 0; d < 16; ++d) acc += qv[d] * pek[ri * 64 + p + d];
        }
        dots[ri] = acc;
    }
#pragma unroll
    for (int ri = 0; ri < 17; ++ri) {
        dots[ri] += __shfl_xor(dots[ri], 1, 64);
        dots[ri] += __shfl_xor(dots[ri], 2, 64);
    }

    const float2 mlv = *(const float2*)(ml + ((size_t)hb * T_SEQ + t) * 2);
    const float m = mlv.x, linv = 1.0f / mlv.y;
    float wv[17];
    float wsum = 0.f;
#pragma unroll
    for (int ri = 0; ri < 17; ++ri) {
        const int s = t - 16 + ri;
        const float wr = (s >= 0) ? __expf(dots[ri] * 0.125f - m) * linv : 0.f;
        wv[ri] = wr;
        wsum += wr;
    }
    wv[0] += 1.0f - wsum;   // far-bucket mass (all s <= t-17)

    float relv[16];
#pragma unroll
    for (int d = 0; d < 16; ++d) relv[d] = 0.f;
#pragma unroll
    for (int ri = 0; ri < 17; ++ri)
#pragma unroll
        for (int d = 0; d < 16; ++d) relv[d] += wv[ri] * pev[ri * 64 + p + d];

    short* op = ao + (size_t)(b * T_SEQ + t) * U_DIM + h * 64 + p;
    bf16x8 a0 = *(const bf16x8*)op, a1 = *(const bf16x8*)(op + 8);
    int4 o0, o1;
    o0.x = packbf(b2f(a0[0]) + relv[0],  b2f(a0[1]) + relv[1]);
    o0.y = packbf(b2f(a0[2]) + relv[2],  b2f(a0[3]) + relv[3]);
    o0.z = packbf(b2f(a0[4]) + relv[4],  b2f(a0[5]) + relv[5]);
    o0.w = packbf(b2f(a0[6]) + relv[6],  b2f(a0[7]) + relv[7]);
    o1.x = packbf(b2f(a1[0]) + relv[8],  b2f(a1[1]) + relv[9]);
    o1.y = packbf(b2f(a1[2]) + relv[10], b2f(a1[3]) + relv[11]);
    o1.z = packbf(b2f(a1[4]) + relv[12], b2f(a1[5]) + relv[13]);
    o1.w = packbf(b2f(a1[6]) + relv[14], b2f(a1[7]) + relv[15]);
    *(int4*)op = o0;
    *(int4*)(op + 8) = o1;
}

// ---------------------------------------------------------------------------
// LayerNorm: one wave per row, shuffle-only reductions.
// ---------------------------------------------------------------------------
__global__ __launch_bounds__(256) void ln_kernel(float* __restrict__ io,
                                                 const float* __restrict__ gamma,
                                                 const float* __restrict__ beta) {
    const int row = blockIdx.x * 4 + (threadIdx.x >> 6);
    const int lane = threadIdx.x & 63;
    float* rp = io + (size_t)row * 512 + lane * 8;
    float4 a = *(const float4*)rp;
    float4 c = *(const float4*)(rp + 4);
    float v[8] = {a.x, a.y, a.z, a.w, c.x, c.y, c.z, c.w};

    float s = v[0] + v[1] + v[2] + v[3] + v[4] + v[5] + v[6] + v[7];
#pragma unroll
    for (int off = 1; off < 64; off <<= 1) s += __shfl_xor(s, off, 64);
    const float mu = s * (1.0f / 512.0f);

    float sq = 0.f;
#pragma unroll
    for (int i = 0; i < 8; ++i) { v[i] -= mu; sq += v[i] * v[i]; }
#pragma unroll
    for (int off = 1; off < 64; off <<= 1) sq += __shfl_xor(sq, off, 64);
    const float rs = rsqrtf(sq * (1.0f / 512.0f) + LN_EPS);

    const float4 g0 = *(const float4*)(gamma + lane * 8);
    const float4 g1 = *(const float4*)(gamma + lane * 8 + 4);
    const float4 b0 = *(const float4*)(beta + lane * 8);
    const float4 b1 = *(const float4*)(beta + lane * 8 + 4);
    float4 o0, o1;
    o0.x = v[0] * rs * g0.x + b0.x;
    o0.y = v[1] * rs * g0.y + b0.y;
    o0.z = v[2] * rs * g0.z + b0.z;
    o0.w = v[3] * rs * g0.w + b0.w;
    o1.x = v[4] * rs * g1.x + b1.x;
    o1.y = v[5] * rs * g1.y + b1.y;
    o1.z = v[6] * rs * g1.z + b1.z;
    o1.w = v[7] * rs * g1.w + b1.w;
    *(float4*)rp = o0;
    *(float4*)(rp + 4) = o1;
}

// ---------------------------------------------------------------------------
extern "C" void kernel_launch(void* const* d_in, const int* in_sizes, int n_in,
                              void* d_out, int out_size, void* d_ws, size_t ws_size,
                              hipStream_t stream) {
    const float* q     = (const float*)d_in[0];
    const float* k     = (const float*)d_in[1];
    const float* v     = (const float*)d_in[2];
    const float* Wq    = (const float*)d_in[3];
    const float* bq    = (const float*)d_in[4];
    const float* Wk    = (const float*)d_in[5];
    const float* bk    = (const float*)d_in[6];
    const float* Wv    = (const float*)d_in[7];
    const float* bv    = (const float*)d_in[8];
    const float* Wo    = (const float*)d_in[9];
    const float* bo    = (const float*)d_in[10];
    const float* gamma = (const float*)d_in[11];
    const float* beta  = (const float*)d_in[12];
    const float* pe_k  = (const float*)d_in[13];
    const float* pe_v  = (const float*)d_in[14];
    float* out = (float*)d_out;

    char* base = (char*)d_ws;
    short* qb = (short*)(base);                          // bf16 raw inputs, 8 MB each
    short* kb = (short*)(base + (((size_t)8) << 20));
    short* vb = (short*)(base + (((size_t)16) << 20));
    short* qe = (short*)(base + (((size_t)24) << 20));   // bf16 Q/K embeddings
    short* ke = (short*)(base + (((size_t)32) << 20));
    short* vT = (short*)(base + (((size_t)40) << 20));   // V embedding transposed [hb][64][1024]
    short* ao = (short*)(base + (((size_t)48) << 20));
    short* wt = (short*)(base + (((size_t)56) << 20));   // 4 x 512 KB bf16 Wt
    float* ml = (float*)(base + (((size_t)58) << 20));   // [64][1024][2] fp32
    short* wtq = wt, *wtk = wt + 262144, *wtv = wt + 2 * 262144, *wto = wt + 3 * 262144;

    prep_all<<<dim3(3328), 256, 0, stream>>>(Wq, Wk, Wv, Wo, wt, q, k, v, qb, kb, vb);
    gemm_nolds<0><<<dim3(64, 4, 3), 256, 0, stream>>>(
        qb, kb, vb, wtq, wtk, wtv, bq, bk, bv, nullptr, qe, ke, vT);
    attn_mfma<<<dim3(8, 64), 256, 0, stream>>>(qe, ke, vT, pe_k, ml, ao);
    band_relv<<<dim3(16, 64), 256, 0, stream>>>(qe, ke, pe_k, pe_v, ml, ao);
    gemm_nolds<1><<<dim3(64, 4, 1), 256, 0, stream>>>(
        ao, ao, ao, wto, wto, wto, bo, bo, bo, q, out, out, out);
    ln_kernel<<<dim3(2048), 256, 0, stream>>>(out, gamma, beta);
}